// Round 2
// baseline (445.619 us; speedup 1.0000x reference)
//
#include <hip/hip_runtime.h>
#include <stdint.h>

// mean(|x|) > 1.0 over D=128  <=>  sum(|x|) > 128.0
#define THRESH_SUM 128.0f

__device__ __forceinline__ float rl(float v, int lane) {
    return __int_as_float(__builtin_amdgcn_readlane(__float_as_int(v), lane));
}

// Wait lgkmcnt(0) only (vmcnt/expcnt bits all-ones): gfx9/CDNA encoding.
__device__ __forceinline__ void lds_fence_wave() {
    __builtin_amdgcn_wave_barrier();
    __builtin_amdgcn_s_waitcnt(0xc07f);
    __builtin_amdgcn_wave_barrier();
}

// Pin occupancy to EXACTLY 3 waves/EU: allows ~170 VGPRs so the 128
// register-resident weight floats stay resident (round-1: compiler targeted
// 6 waves/EU, capped at 84 VGPRs, and refetched weights every iteration).
__global__ __launch_bounds__(256)
__attribute__((amdgpu_waves_per_eu(3, 3)))
void dyn_mlp_kernel(const float* __restrict__ x,
                    const float* __restrict__ W1, const float* __restrict__ b1,
                    const float* __restrict__ W2, const float* __restrict__ b2,
                    const float* __restrict__ Wf, const float* __restrict__ bf,
                    float* __restrict__ out, int B)
{
    // per-wave double-buffered x staging: 2 rows x 128 floats x 2 buffers
    __shared__ float xbuf[4][512];

    const int tid  = threadIdx.x;
    const int wave = tid >> 6;
    const int lane = tid & 63;
    const int u    = lane & 31;   // branch-2 unit index (0..31)
    const int h    = lane >> 5;   // which k-half (0..1)

    // ---- preload weights into registers (per-lane slices) ----
    // w2r[j] = W2[u][64*h + j],  j = 0..63   (W2 is (32,128) row-major)
    float w2r[64];
    #pragma unroll
    for (int t = 0; t < 16; ++t) {
        const float4 v = *(const float4*)&W2[u * 128 + h * 64 + 4 * t];
        w2r[4*t+0] = v.x; w2r[4*t+1] = v.y; w2r[4*t+2] = v.z; w2r[4*t+3] = v.w;
    }
    // lane stores outputs d0=2*lane, d1=2*lane+1;   Wf is (128,64) row-major
    const int d0 = 2 * lane, d1 = 2 * lane + 1;
    float wf0[32], wf1[32];
    #pragma unroll
    for (int t = 0; t < 8; ++t) {
        const float4 a = *(const float4*)&Wf[d0 * 64 + 4 * t];
        wf0[4*t+0] = a.x; wf0[4*t+1] = a.y; wf0[4*t+2] = a.z; wf0[4*t+3] = a.w;
        const float4 b = *(const float4*)&Wf[d1 * 64 + 4 * t];
        wf1[4*t+0] = b.x; wf1[4*t+1] = b.y; wf1[4*t+2] = b.z; wf1[4*t+3] = b.w;
    }
    const float b2u = b2[u];
    const float bf0 = bf[d0], bf1 = bf[d1];

    const long long NP = (long long)(B >> 1);        // row pairs
    const int gw = blockIdx.x * 4 + wave;            // global wave id
    const int nw = gridDim.x * 4;                    // total waves

    long long pair = gw;
    float4 xv = make_float4(0.f, 0.f, 0.f, 0.f);
    if (pair < NP) xv = *(const float4*)&x[pair * 256 + lane * 4];

    int par = 0;
    for (; pair < NP; pair += nw, par ^= 1) {
        const float4 xc = xv;
        // prefetch next pair (1 KB per wave in flight)
        const long long nxt = pair + nw;
        if (nxt < NP) xv = *(const float4*)&x[nxt * 256 + lane * 4];

        // |x| partial sum; lanes 0-31 hold row 0, lanes 32-63 row 1
        float sa = (fabsf(xc.x) + fabsf(xc.y)) + (fabsf(xc.z) + fabsf(xc.w));
        sa += __shfl_xor(sa, 1);
        sa += __shfl_xor(sa, 2);
        sa += __shfl_xor(sa, 4);
        sa += __shfl_xor(sa, 8);
        sa += __shfl_xor(sa, 16);   // every lane of a half: full |x| sum of its row

        // stage the pair's x into per-wave LDS (double-buffered by parity)
        float* xw = &xbuf[wave][0] + (par ? 256 : 0);
        *(float4*)&xw[lane * 4] = xc;
        lds_fence_wave();

        #pragma unroll
        for (int p = 0; p < 2; ++p) {
            // ---- stage 1: o2[u] = relu(x . W2[u] + b2[u]) ----
            // 4-way split accumulators: chain length 16 instead of 64
            float ac0 = 0.f, ac1 = 0.f, ac2 = 0.f, ac3 = 0.f;
            const float* xr = &xw[p * 128 + h * 64];
            #pragma unroll
            for (int t = 0; t < 16; ++t) {
                const float4 q = *(const float4*)&xr[4 * t];  // broadcast read
                ac0 = fmaf(q.x, w2r[4*t+0], ac0);
                ac1 = fmaf(q.y, w2r[4*t+1], ac1);
                ac2 = fmaf(q.z, w2r[4*t+2], ac2);
                ac3 = fmaf(q.w, w2r[4*t+3], ac3);
            }
            float acc = (ac0 + ac1) + (ac2 + ac3);
            acc += __shfl_xor(acc, 32);                 // combine k-halves
            const float o2v = fmaxf(acc + b2u, 0.f);

            // ---- stage 2: out[d] = sum_u o2[u]*Wf[d][u] + bf[d] ----
            // 2x2 split accumulators: chain length 16
            float a0e = bf0, a0o = 0.f, a1e = bf1, a1o = 0.f;
            #pragma unroll
            for (int uu = 0; uu < 32; uu += 2) {
                const float t0 = rl(o2v, uu);           // SGPR broadcast
                const float t1 = rl(o2v, uu + 1);
                a0e = fmaf(t0, wf0[uu],     a0e);
                a1e = fmaf(t0, wf1[uu],     a1e);
                a0o = fmaf(t1, wf0[uu + 1], a0o);
                a1o = fmaf(t1, wf1[uu + 1], a1o);
            }
            float a0 = a0e + a0o, a1 = a1e + a1o;

            // ---- rare branch-1 fixup (mean|x| > 1, ~0.01% of rows) ----
            const float sp = rl(sa, p * 32);            // row p's |x| sum (uniform)
            if (__builtin_expect(sp > THRESH_SUM, 0)) {
                // o1[lane] = relu(x . W1[lane] + b1[lane]), 64 units
                float od = 0.f;
                #pragma unroll 4
                for (int t = 0; t < 32; ++t) {
                    const float4 q  = *(const float4*)&xw[p * 128 + 4 * t];
                    const float4 wv = *(const float4*)&W1[lane * 128 + 4 * t];
                    od = fmaf(q.x, wv.x, od);
                    od = fmaf(q.y, wv.y, od);
                    od = fmaf(q.z, wv.z, od);
                    od = fmaf(q.w, wv.w, od);
                }
                const float o1v = fmaxf(od + b1[lane], 0.f);
                a0 = bf0; a1 = bf1;
                #pragma unroll 4
                for (int uu = 0; uu < 64; ++uu) {
                    const float tv = rl(o1v, uu);
                    a0 = fmaf(tv, Wf[d0 * 64 + uu], a0);
                    a1 = fmaf(tv, Wf[d1 * 64 + uu], a1);
                }
            }

            const long long row = pair * 2 + p;
            *(float2*)&out[row * 128 + d0] = make_float2(a0, a1);
        }
    }
}

extern "C" void kernel_launch(void* const* d_in, const int* in_sizes, int n_in,
                              void* d_out, int out_size, void* d_ws, size_t ws_size,
                              hipStream_t stream) {
    const float* x  = (const float*)d_in[0];
    const float* W1 = (const float*)d_in[1];
    const float* b1 = (const float*)d_in[2];
    const float* W2 = (const float*)d_in[3];
    const float* b2 = (const float*)d_in[4];
    const float* Wf = (const float*)d_in[5];
    const float* bf = (const float*)d_in[6];
    float* out = (float*)d_out;

    const int B = in_sizes[0] / 128;   // D = 128

    // 768 blocks x 256 threads = 3072 waves = exactly 3 blocks/CU resident
    dim3 grid(768), block(256);
    hipLaunchKernelGGL(dyn_mlp_kernel, grid, block, 0, stream,
                       x, W1, b1, W2, b2, Wf, bf, out, B);
}

// Round 3
// 263.411 us; speedup vs baseline: 1.6917x; 1.6917x over previous
//
#include <hip/hip_runtime.h>
#include <stdint.h>

// mean(|x|) > 1.0 over D=128  <=>  sum(|x|) > 128.0
// Rows with bf16-estimated sum|x| > FLAG_THRESH go to the exact-fp32 fixup
// kernel (covers all branch-1 rows plus borderline rows; ~35 of 262144).
#define FLAG_THRESH 127.0f

typedef short bfrag __attribute__((ext_vector_type(8)));   // 8 bf16 (4 VGPRs)
typedef float floatx4 __attribute__((ext_vector_type(4))); // MFMA acc
typedef int intx4 __attribute__((ext_vector_type(4)));

__device__ __forceinline__ unsigned bf16pk(float a, float b) {  // RNE pack
    unsigned ua = __float_as_uint(a), ub = __float_as_uint(b);
    ua = (ua + 0x7fffu + ((ua >> 16) & 1u)) >> 16;
    ub = (ub + 0x7fffu + ((ub >> 16) & 1u)) & 0xffff0000u;
    return ua | ub;
}
__device__ __forceinline__ unsigned short bf16s(float a) {      // RNE scalar
    unsigned ua = __float_as_uint(a);
    return (unsigned short)((ua + 0x7fffu + ((ua >> 16) & 1u)) >> 16);
}
__device__ __forceinline__ bfrag mkfrag(unsigned a, unsigned b, unsigned c, unsigned d) {
    intx4 v = {(int)a, (int)b, (int)c, (int)d};
    return __builtin_bit_cast(bfrag, v);
}
// lgkmcnt(0)-only wait (vmcnt/expcnt bits all-ones), wave-local
__device__ __forceinline__ void lds_fence_wave() {
    __builtin_amdgcn_wave_barrier();
    __builtin_amdgcn_s_waitcnt(0xc07f);
    __builtin_amdgcn_wave_barrier();
}

// ---------------------------------------------------------------------------
// Main kernel: branch-2 path for ALL rows via bf16 MFMA; flags suspicious rows.
//   stage1: S(16x32) = x(16x128) @ W2^T  (+ ones-column for sum|x|)
//   H = relu(S + b2)  -> LDS (bf16)
//   stage2 (transposed): out^T(128x16) = Wf[:, :32](128x32) @ H^T(32x16)
// 512 blocks x 256 thr = 2048 waves; each wave: ntiles/2048 16-row tiles.
// ---------------------------------------------------------------------------
__global__ __launch_bounds__(256, 2)
void dyn_main(const float* __restrict__ x, const float* __restrict__ W2,
              const float* __restrict__ b2, const float* __restrict__ Wf,
              const float* __restrict__ bf, float* __restrict__ out,
              int ntiles, int* __restrict__ ws, int cap)
{
    // weight fragments pre-gathered in lane order -> conflict-free b128 reads
    __shared__ __align__(16) short w2f[8][64][8];   // [ks*2+nb][lane][j]
    __shared__ __align__(16) short wff[8][64][8];   // [mb][lane][j]
    __shared__ __align__(16) float bfl[128];
    __shared__ __align__(16) short hbuf[4][16 * 40]; // per-wave H, stride 40

    const int tid  = threadIdx.x;
    const int wave = tid >> 6, lane = tid & 63;
    const int l15  = lane & 15, q = lane >> 4;

    // ---- stage weights into LDS (once per block) ----
    for (int idx = tid; idx < 4096; idx += 256) {
        const int j = idx & 7, ln = (idx >> 3) & 63, blk = idx >> 9;
        // W2 frag: blk = ks*2+nb ; element W2[nb*16 + (ln&15)][ks*32 + (ln>>4)*8 + j]
        const int ks = blk >> 1, nb = blk & 1;
        const int u = nb * 16 + (ln & 15);
        const int k = ks * 32 + ((ln >> 4) << 3) + j;
        ((short*)w2f)[idx] = (short)bf16s(W2[u * 128 + k]);
        // Wf frag: blk = mb ; element Wf[mb*16 + (ln&15)][(ln>>4)*8 + j], c < 32
        const int d = blk * 16 + (ln & 15);
        const int c = ((ln >> 4) << 3) + j;
        ((short*)wff)[idx] = (short)bf16s(Wf[d * 64 + c]);
    }
    for (int i = tid; i < 128; i += 256) bfl[i] = bf[i];
    const float b2r0 = b2[l15], b2r1 = b2[16 + l15];
    __syncthreads();

    // ones-column B fragment: B[k][n] = (n==0) ? 1.0bf16 : 0
    const unsigned ov = (l15 == 0) ? 0x3f803f80u : 0u;
    const bfrag onesf = mkfrag(ov, ov, ov, ov);

    const int wid = blockIdx.x * 4 + wave;
    const int wstride = gridDim.x * 4;

    long long cur = wid;
    bool more = cur < ntiles;
    floatx4 xl[8];
    if (more) {
        const float* base = x + cur * 2048 + l15 * 128 + q * 8;
        #pragma unroll
        for (int ks = 0; ks < 4; ++ks) {
            xl[2 * ks]     = *(const floatx4*)(base + ks * 32);
            xl[2 * ks + 1] = *(const floatx4*)(base + ks * 32 + 4);
        }
    }

    while (more) {
        const long long nxt = cur + wstride;
        const bool hasnxt = nxt < ntiles;
        floatx4 xc[8];
        #pragma unroll
        for (int i = 0; i < 8; ++i) xc[i] = xl[i];
        if (hasnxt) {   // register prefetch of next tile (kept in flight)
            const float* base = x + nxt * 2048 + l15 * 128 + q * 8;
            #pragma unroll
            for (int ks = 0; ks < 4; ++ks) {
                xl[2 * ks]     = *(const floatx4*)(base + ks * 32);
                xl[2 * ks + 1] = *(const floatx4*)(base + ks * 32 + 4);
            }
        }

        // ---- stage 1 ----
        floatx4 a0 = {0.f, 0.f, 0.f, 0.f}, a1 = a0, asum = a0;
        #pragma unroll
        for (int ks = 0; ks < 4; ++ks) {
            const floatx4 p = xc[2 * ks], r = xc[2 * ks + 1];
            const unsigned u0 = bf16pk(p[0], p[1]), u1 = bf16pk(p[2], p[3]);
            const unsigned u2 = bf16pk(r[0], r[1]), u3 = bf16pk(r[2], r[3]);
            const bfrag af = mkfrag(u0, u1, u2, u3);
            const bfrag aa = mkfrag(u0 & 0x7fff7fffu, u1 & 0x7fff7fffu,
                                    u2 & 0x7fff7fffu, u3 & 0x7fff7fffu);
            const bfrag w0 = *(const bfrag*)&w2f[ks * 2 + 0][lane][0];
            const bfrag w1 = *(const bfrag*)&w2f[ks * 2 + 1][lane][0];
            a0   = __builtin_amdgcn_mfma_f32_16x16x32_bf16(af, w0, a0, 0, 0, 0);
            a1   = __builtin_amdgcn_mfma_f32_16x16x32_bf16(af, w1, a1, 0, 0, 0);
            asum = __builtin_amdgcn_mfma_f32_16x16x32_bf16(aa, onesf, asum, 0, 0, 0);
        }

        // H = relu(S + b2) -> LDS bf16.  C-layout: row=q*4+reg, col=nb*16+l15
        short* hb = &hbuf[wave][0];
        #pragma unroll
        for (int reg = 0; reg < 4; ++reg) {
            const int row = q * 4 + reg;
            hb[row * 40 + l15]      = (short)bf16s(fmaxf(a0[reg] + b2r0, 0.f));
            hb[row * 40 + 16 + l15] = (short)bf16s(fmaxf(a1[reg] + b2r1, 0.f));
        }

        // flag branch-1 / borderline rows (abs-sums live in col 0 -> l15==0)
        if (l15 == 0) {
            #pragma unroll
            for (int reg = 0; reg < 4; ++reg) {
                if (asum[reg] > FLAG_THRESH) {
                    const int row = (int)(cur * 16) + q * 4 + reg;
                    const int slot = atomicAdd(ws, 1);
                    if (slot < cap) ws[4 + slot] = row;
                }
            }
        }

        lds_fence_wave();

        // ---- stage 2 (transposed): A = Wf slice, B = H^T ----
        const bfrag hfrag = *(const bfrag*)&hb[l15 * 40 + q * 8];
        floatx4 o[8];
        #pragma unroll
        for (int mb = 0; mb < 8; ++mb) o[mb] = (floatx4){0.f, 0.f, 0.f, 0.f};
        #pragma unroll
        for (int mb = 0; mb < 8; ++mb) {
            const bfrag wfr = *(const bfrag*)&wff[mb][lane][0];
            o[mb] = __builtin_amdgcn_mfma_f32_16x16x32_bf16(wfr, hfrag, o[mb], 0, 0, 0);
        }

        // C-layout: lane holds out[row = cur*16 + l15][d = mb*16 + q*4 + reg]
        float* obase = out + (cur * 16 + l15) * 128 + q * 4;
        #pragma unroll
        for (int mb = 0; mb < 8; ++mb) {
            const floatx4 bv = *(const floatx4*)&bfl[mb * 16 + q * 4];
            const floatx4 v = o[mb] + bv;
            *(floatx4*)(obase + mb * 16) = v;
        }

        lds_fence_wave();   // hfrag read drained before next iter's H writes
        cur = nxt; more = hasnxt;
    }
}

// ---------------------------------------------------------------------------
// Fixup: exact fp32 recompute (both branches) for flagged rows. One wave/row.
// ---------------------------------------------------------------------------
__global__ __launch_bounds__(256)
void dyn_fixup(const float* __restrict__ x, const float* __restrict__ W1,
               const float* __restrict__ b1, const float* __restrict__ W2,
               const float* __restrict__ b2, const float* __restrict__ Wf,
               const float* __restrict__ bf, float* __restrict__ out,
               const int* __restrict__ ws, int cap)
{
    __shared__ float xr[4][128];
    __shared__ float hh[4][64];
    const int wave = threadIdx.x >> 6, lane = threadIdx.x & 63;
    int n = ws[0]; if (n > cap) n = cap;
    for (int i = blockIdx.x * 4 + wave; i < n; i += gridDim.x * 4) {
        const int r = ws[4 + i];
        const float2 xv = *(const float2*)&x[(long long)r * 128 + lane * 2];
        float s = fabsf(xv.x) + fabsf(xv.y);
        #pragma unroll
        for (int d = 1; d < 64; d <<= 1) s += __shfl_xor(s, d);
        xr[wave][lane * 2] = xv.x; xr[wave][lane * 2 + 1] = xv.y;
        lds_fence_wave();
        float hv = 0.f;
        if (s > 128.0f) {                    // branch 1: 64 units of W1
            float a = 0.f;
            for (int k = 0; k < 128; k += 4) {
                const float4 qq = *(const float4*)&xr[wave][k];
                const float4 wv = *(const float4*)&W1[lane * 128 + k];
                a = fmaf(qq.x, wv.x, a); a = fmaf(qq.y, wv.y, a);
                a = fmaf(qq.z, wv.z, a); a = fmaf(qq.w, wv.w, a);
            }
            hv = fmaxf(a + b1[lane], 0.f);
        } else if (lane < 32) {              // branch 2: 32 units of W2
            float a = 0.f;
            for (int k = 0; k < 128; k += 4) {
                const float4 qq = *(const float4*)&xr[wave][k];
                const float4 wv = *(const float4*)&W2[lane * 128 + k];
                a = fmaf(qq.x, wv.x, a); a = fmaf(qq.y, wv.y, a);
                a = fmaf(qq.z, wv.z, a); a = fmaf(qq.w, wv.w, a);
            }
            hv = fmaxf(a + b2[lane], 0.f);
        }
        hh[wave][lane] = hv;                 // zero-padded for branch 2
        lds_fence_wave();
        #pragma unroll
        for (int jj = 0; jj < 2; ++jj) {
            const int d = lane + 64 * jj;
            float a = bf[d];
            for (int u = 0; u < 64; ++u) a = fmaf(hh[wave][u], Wf[d * 64 + u], a);
            out[(long long)r * 128 + d] = a;
        }
        lds_fence_wave();
    }
}

extern "C" void kernel_launch(void* const* d_in, const int* in_sizes, int n_in,
                              void* d_out, int out_size, void* d_ws, size_t ws_size,
                              hipStream_t stream) {
    const float* x  = (const float*)d_in[0];
    const float* W1 = (const float*)d_in[1];
    const float* b1 = (const float*)d_in[2];
    const float* W2 = (const float*)d_in[3];
    const float* b2 = (const float*)d_in[4];
    const float* Wf = (const float*)d_in[5];
    const float* bf = (const float*)d_in[6];
    float* out = (float*)d_out;

    const int B = in_sizes[0] / 128;   // D = 128
    const int ntiles = B / 16;         // 16384 for B=262144
    const int cap = (int)((ws_size > 16) ? ((ws_size - 16) / 4) : 0);

    hipMemsetAsync(d_ws, 0, 16, stream);   // zero the flagged-row counter
    // 512 blocks = exactly 2 blocks/CU resident -> balanced, zero tail
    hipLaunchKernelGGL(dyn_main, dim3(512), dim3(256), 0, stream,
                       x, W2, b2, Wf, bf, out, ntiles, (int*)d_ws, cap);
    hipLaunchKernelGGL(dyn_fixup, dim3(64), dim3(256), 0, stream,
                       x, W1, b1, W2, b2, Wf, bf, out, (int*)d_ws, cap);
}